// Round 2
// baseline (3989.293 us; speedup 1.0000x reference)
//
#include <hip/hip_runtime.h>

#define B_  256
#define T_  512
#define F_  64
#define H_  1024
#define TL_ 64

typedef _Float16 half8 __attribute__((ext_vector_type(8)));
typedef float   floatx4 __attribute__((ext_vector_type(4)));
typedef unsigned long long ull;

#define MFMA(a, b, c) __builtin_amdgcn_mfma_f32_16x16x32_f16(a, b, c, 0, 0, 0)

// ws layout (bytes)
#define WF_E   0UL          // W_hh enc fragments: 3*64*32 chunks * 1024B
#define WF_D   6291456UL    // W_hh dec fragments
#define WF_I   12582912UL   // W_ih enc fragments: 3*64*2 chunks * 1024B
#define HP     12976128UL   // h planes: [2 parity][hi fp16 512KB]
#define PSTR   524288UL     // parity stride
#define PB     15073280UL   // fc partials: [2][64 jg][256 rows] f32
#define BARS   15204352UL   // 16 group counters, 128B apart (+dbar at uint 1)
// h plane (fragment-major fp16): [rg 16][kb 32][lane 64][16B]; slab 32KB/rg;
// block (rg,cb) owns the contiguous 2KB at rg*32768 + cb*2048.
// NOTE (r10): h stored fp16-only; own-recurrence stays fp32 in hold[].
// NOTE (r12): r11 hung — suspected gbar_loc (workgroup RMW + asm sc0 spin).
// This round keeps the LLC barrier EVERYWHERE (r10-proven) and localizes
// only the DATA plane: in loc mode h' goes via plain stores (dirty in own
// XCD L2) and the staging DMA reads with sc0 (bypass L1, hit that L2).
// Ordering: plain store acked at L2 (vmcnt drain in __syncthreads) BEFORE
// the LLC counter increment; consumer sees counter, then sc0-reads the
// same L2. The xmap transiently uses the first 1KB of PB; PB is fully
// re-written at decoder d=0 before its first read at d=1.

// LLC-coherent scalar atomics (sc0 sc1: bypass L1/L2, coherent at IF).
__device__ __forceinline__ void sta8(void* p, ull v) {
  __hip_atomic_store((ull*)p, v, __ATOMIC_RELAXED, __HIP_MEMORY_SCOPE_AGENT);
}
__device__ __forceinline__ float lda4f(const float* p) {
  return __hip_atomic_load(p, __ATOMIC_RELAXED, __HIP_MEMORY_SCOPE_AGENT);
}
__device__ __forceinline__ unsigned lda4u(const unsigned* p) {
  return __hip_atomic_load(p, __ATOMIC_RELAXED, __HIP_MEMORY_SCOPE_AGENT);
}

// ---------------------------------------------------------------------------
// Setup: W_hh (enc,dec) and W_ih (enc) fp32 -> fp16 MFMA-B fragment layout.
// B-frag 16x16x32: lane L holds B[k=(L>>4)*8+t][n=L&15] ->
// W[g*H + jg*16 + (L&15)][kb*32 + (L>>4)*8 + t].
// Chunk c = (((g*64+jg)*32 + kb)*4 + q)*16 + r ; 16B per chunk-lane.
// ---------------------------------------------------------------------------
__global__ void gru_setup(const float* __restrict__ WhhE,
                          const float* __restrict__ WhhD,
                          const float* __restrict__ WihE,
                          char* __restrict__ ws) {
  int t = blockIdx.x * 256 + threadIdx.x;
  if (t < 512) ((unsigned int*)(ws + BARS))[t] = 0u;
  const int NW = 3 * 64 * 32 * 4 * 16;
  if (t < 2 * NW) {
    const float* W = (t < NW) ? WhhE : WhhD;
    size_t dst = (t < NW) ? WF_E : WF_D;
    int c = (t < NW) ? t : t - NW;
    int r = c & 15, q = (c >> 4) & 3, kb = (c >> 6) & 31, gj = c >> 11;
    int row = (gj >> 6) * H_ + (gj & 63) * 16 + r;
    const float* src = W + (size_t)row * H_ + kb * 32 + q * 8;
    half8 v;
#pragma unroll
    for (int i = 0; i < 8; ++i) v[i] = (_Float16)src[i];
    *(half8*)(ws + dst + (size_t)c * 16) = v;
  } else if (t < 2 * NW + 3 * 64 * 2 * 4 * 16) {
    int c = t - 2 * NW;
    int r = c & 15, q = (c >> 4) & 3, kc = (c >> 6) & 1, gj = c >> 7;
    int row = (gj >> 6) * H_ + (gj & 63) * 16 + r;
    const float* src = WihE + (size_t)row * F_ + kc * 32 + q * 8;
    half8 v;
#pragma unroll
    for (int i = 0; i < 8; ++i) v[i] = (_Float16)src[i];
    *(half8*)(ws + WF_I + (size_t)c * 16) = v;
  }
}

// Group barrier: 16 blocks (same rg), own cacheline, relaxed LLC atomics.
// (r10-proven mechanism; used in BOTH modes — see r12 note above.)
__device__ __forceinline__ void gbar(unsigned int* cnt, unsigned int target) {
  __syncthreads();
  if (threadIdx.x == 0) {
    __hip_atomic_fetch_add(cnt, 1u, __ATOMIC_RELAXED,
                           __HIP_MEMORY_SCOPE_AGENT);
    while (__hip_atomic_load(cnt, __ATOMIC_RELAXED,
                             __HIP_MEMORY_SCOPE_AGENT) < target)
      __builtin_amdgcn_s_sleep(1);
  }
  __syncthreads();
}

// ---------------------------------------------------------------------------
// Main persistent kernel: 256 blocks x 512 thr. Block (rg, cb): rows
// [rg*16,+16), h-cols [cb*64,+64). Wave w: jp=w&3 (jg=cb*4+jp), kh=w>>2.
// r12: rg-groups are formed from the PHYSICAL XCD (HW_REG_XCC_ID + one
// device barrier on the r10 LLC-spin mechanism). When every XCD hosts
// exactly 32 blocks (2 groups of 16), the per-step h exchange rides the
// per-XCD L2 (plain stores -> dirty L2; sc0 DMA reads hit it) instead of
// the LLC coherent fabric that bound r10 at ~4.75us/step. Barriers stay on
// the LLC path in both modes. Unbalanced dispatch -> loc=0 fallback,
// bit-identical to the r10 champion.
// ---------------------------------------------------------------------------
__global__ __launch_bounds__(512, 2) void gru_main(
    const float* __restrict__ x,
    const float* __restrict__ bih_e, const float* __restrict__ bhh_e,
    const float* __restrict__ Wih_d,
    const float* __restrict__ bih_d, const float* __restrict__ bhh_d,
    const float* __restrict__ fcW, const float* __restrict__ fcb,
    float* __restrict__ out, char* __restrict__ ws) {

  __shared__ __align__(128) char atile[32768];  // [kb 32][L 64][16B]
  __shared__ float red[4 * 64 * 17];            // kh1 partials [jp][L][17]
  __shared__ __align__(16) char otile[2048];    // h' image (2KB)
  __shared__ float inp_lds[16];
  __shared__ unsigned char xmap[256];
  __shared__ int disc[3];                       // rg, cb, loc

  const int tid = threadIdx.x;
  const int L = tid & 63;
  const int w = tid >> 6;
  const int jp = w & 3;
  const int kh = w >> 2;
  const int bx = blockIdx.x;
  const int r = L & 15;
  const int q = L >> 4;

  // ---- XCD discovery prologue (runs once; LLC-spin mechanism = r10's) ----
  {
    unsigned* map = (unsigned*)(ws + PB);
    unsigned* dbar = (unsigned*)(ws + BARS) + 1;
    if (tid == 0) {
      unsigned xcc;
      asm volatile("s_getreg_b32 %0, hwreg(HW_REG_XCC_ID)" : "=s"(xcc));
      __hip_atomic_store(map + bx, xcc & 15u, __ATOMIC_RELAXED,
                         __HIP_MEMORY_SCOPE_AGENT);
    }
    __syncthreads();  // drains vmcnt: map store is at the LLC
    if (tid == 0) {
      __hip_atomic_fetch_add(dbar, 1u, __ATOMIC_RELAXED,
                             __HIP_MEMORY_SCOPE_AGENT);
      while (lda4u(dbar) < 256u) __builtin_amdgcn_s_sleep(1);
    }
    __syncthreads();
    if (tid < 256) xmap[tid] = (unsigned char)(lda4u(map + tid) & 255u);
    __syncthreads();
    if (tid == 0) {
      int cnt[8] = {0, 0, 0, 0, 0, 0, 0, 0};
      int myx = xmap[bx], rank = 0, ok = 1;
      for (int i = 0; i < 256; ++i) {
        int xi = xmap[i];
        if (xi > 7) { ok = 0; break; }
        cnt[xi]++;
        if (i < bx && xi == myx) rank++;
      }
      if (ok)
        for (int i = 0; i < 8; ++i) ok &= (cnt[i] == 32);
      if (ok) {
        disc[0] = myx * 2 + (rank >> 4);  // 2 rgs per XCD
        disc[1] = rank & 15;
        disc[2] = 1;
      } else {
        disc[0] = bx & 15;                // r10 static mapping, LLC path
        disc[1] = bx >> 4;
        disc[2] = 0;
      }
    }
    __syncthreads();
  }
  const int rg = disc[0];
  const int cb = disc[1];
  const int loc = disc[2];  // globally uniform: every block saw the same map

  const int jg = cb * 4 + jp;
  const int jc = jg * 16 + r;

  unsigned int* bar = (unsigned int*)(ws + BARS) + (size_t)rg * 32;
  unsigned int bt = 0;

  const size_t slab = (size_t)rg * 32768;

  // zero own h'-region of parity 0 (2KB/block). Always LLC: in loc mode the
  // first sc0 read misses L2 and fills from LLC -> sees the zeros (no stale
  // dirty lines: end-of-dispatch performs agent release = L2 wb+inv).
  if (tid < 256) {
    sta8(ws + HP + slab + (size_t)cb * 2048 + (size_t)tid * 8, 0ull);
  }

  float hold[4] = {0.f, 0.f, 0.f, 0.f};
  const float fcb_s = *fcb;
  const float fcw_l = fcW[jc];

  bt += 16;
  gbar(bar, bt);

  for (int phase = 0; phase < 2; ++phase) {
    // register-resident W_hh B-frags for (jg, kh): [gate][kk].
    half8 bW[48];
    {
      const char* wf = ws + (phase ? WF_D : WF_E);
#pragma unroll
      for (int g = 0; g < 3; ++g)
#pragma unroll
        for (int kk = 0; kk < 16; ++kk)
          bW[g * 16 + kk] = *(const half8*)(
              wf + (size_t)((g * 64 + jg) * 32 + kh * 16 + kk) * 1024 +
              (size_t)L * 16);
#pragma unroll
      for (int i = 0; i < 48; ++i) asm volatile("" : "+v"(bW[i]));
    }
    const float* bih = phase ? bih_d : bih_e;
    const float* bhh = phase ? bhh_d : bhh_e;
    const float b_r  = bih[jc]          + bhh[jc];
    const float b_z  = bih[H_ + jc]     + bhh[H_ + jc];
    const float b_in = bih[2 * H_ + jc];
    const float b_hn = bhh[2 * H_ + jc];
    float wd_r = 0.f, wd_z = 0.f, wd_n = 0.f;
    if (phase) {
      wd_r = Wih_d[jc]; wd_z = Wih_d[H_ + jc]; wd_n = Wih_d[2 * H_ + jc];
    }

    const int nsteps = phase ? TL_ : T_;
    for (int d = 0; d < nsteps; ++d) {
      const int s = phase ? T_ + d : d;

      // ---- stage A slab (32KB) via async global->LDS DMA.
      //      loc: aux 1 (sc0, bypass L1, hit own-XCD L2); else aux 17
      //      (sc0|sc1, LLC-coherent). 32 segs of 1KB; wave w takes segs
      //      w*4..w*4+3; lane L's 16B lands at seg base + L*16. ----
      {
        const char* srcbase = ws + HP + (size_t)(s & 1) * PSTR + slab;
        if (loc) {
#pragma unroll
          for (int c = 0; c < 4; ++c) {
            const int seg = w * 4 + c;  // 0..31
            const char* src = srcbase + (size_t)seg * 1024 + (size_t)L * 16;
            __builtin_amdgcn_global_load_lds(
                (const __attribute__((address_space(1))) void*)src,
                (__attribute__((address_space(3))) void*)(atile + seg * 1024),
                16, 0, 1);
          }
        } else {
#pragma unroll
          for (int c = 0; c < 4; ++c) {
            const int seg = w * 4 + c;
            const char* src = srcbase + (size_t)seg * 1024 + (size_t)L * 16;
            __builtin_amdgcn_global_load_lds(
                (const __attribute__((address_space(1))) void*)src,
                (__attribute__((address_space(3))) void*)(atile + seg * 1024),
                16, 0, 17);
          }
        }
      }

      // ---- decoder scalar input (overlaps the staging DMA; pb stays on
      //      the LLC path in both modes — small, and only agent ops ever
      //      touch PB so no L2/LLC mixing) ----
      if (phase && tid < 16) {
        float sum = 0.f;
        if (d > 0) {
          const float* pb =
              (const float*)(ws + PB) + (size_t)((d + 1) & 1) * 64 * 256;
          int row = rg * 16 + tid;
          float a = fcb_s;
          for (int jj = 0; jj < 64; ++jj) a += lda4f(&pb[jj * 256 + row]);
          sum = a;
          if (cb == 0) out[(size_t)row * TL_ + (d - 1)] = a;
        }
        inp_lds[tid] = sum;
      }
      __syncthreads();  // drains vmcnt -> DMA complete

      floatx4 a0 = {0.f, 0.f, 0.f, 0.f}, a1 = {0.f, 0.f, 0.f, 0.f};
      floatx4 a2 = {0.f, 0.f, 0.f, 0.f}, aI = {0.f, 0.f, 0.f, 0.f};

      // ---- h-GEMM, this wave's K-half (stride-1 ds_read_b128) ----
#pragma unroll
      for (int kk = 0; kk < 16; ++kk) {
        const int kb = kh * 16 + kk;
        half8 ahi = *(const half8*)(atile + kb * 1024 + L * 16);
        a0 = MFMA(ahi, bW[kk], a0);
        a1 = MFMA(ahi, bW[16 + kk], a1);
        a2 = MFMA(ahi, bW[32 + kk], a2);
      }

      // ---- kh1: encoder x-projection + dump partials ----
      if (kh == 1) {
        if (!phase) {
          const float* xp =
              x + ((size_t)(rg * 16 + r) * T_ + s) * F_ + q * 8;
          const char* wfi = ws + WF_I + (size_t)L * 16;  // L1/L2-hot reloads
#pragma unroll
          for (int kc = 0; kc < 2; ++kc) {
            floatx4 x0 = *(const floatx4*)(xp + kc * 32);
            floatx4 x1 = *(const floatx4*)(xp + kc * 32 + 4);
            half8 xa;
#pragma unroll
            for (int i = 0; i < 4; ++i) {
              xa[i] = (_Float16)x0[i];
              xa[4 + i] = (_Float16)x1[i];
            }
            a0 = MFMA(xa, *(const half8*)(wfi +
                     (size_t)((0 * 64 + jg) * 2 + kc) * 1024), a0);
            a1 = MFMA(xa, *(const half8*)(wfi +
                     (size_t)((1 * 64 + jg) * 2 + kc) * 1024), a1);
            aI = MFMA(xa, *(const half8*)(wfi +
                     (size_t)((2 * 64 + jg) * 2 + kc) * 1024), aI);
          }
        }
        float* rd = &red[(jp * 64 + L) * 17];
#pragma unroll
        for (int i = 0; i < 4; ++i) {
          rd[i] = a0[i];
          rd[4 + i] = a1[i];
          rd[8 + i] = a2[i];
        }
        if (!phase) {
#pragma unroll
          for (int i = 0; i < 4; ++i) rd[12 + i] = aI[i];
        }
      }
      __syncthreads();

      // ---- kh0: reduce halves, gate epilogue, h' -> otile ----
      if (kh == 0) {
        const float* rd = &red[(jp * 64 + L) * 17];
        const size_t tbase = (size_t)(jp >> 1) * 1024 +
                             (size_t)((jp & 1) * 2 + (r >> 3)) * 256 +
                             (size_t)(r & 7) * 2;
        float pv[4];
#pragma unroll
        for (int i = 0; i < 4; ++i) {
          float rpre = a0[i] + rd[i] + b_r;
          float zpre = a1[i] + rd[4 + i] + b_z;
          float hn   = a2[i] + rd[8 + i] + b_hn;
          float inn  = b_in + (phase ? 0.f : rd[12 + i]);
          if (phase) {
            float inp = inp_lds[q * 4 + i];
            rpre += inp * wd_r;
            zpre += inp * wd_z;
            inn  += inp * wd_n;
          }
          float rg_ = 1.f / (1.f + __expf(-rpre));
          float zg = 1.f / (1.f + __expf(-zpre));
          float t2 = __expf(-2.f * (inn + rg_ * hn));
          float ng = 2.f / (1.f + t2) - 1.f;  // tanh, safe at +-inf
          float hnew = (1.f - zg) * ng + zg * hold[i];
          hold[i] = hnew;  // fp32 carry: storage quant never compounds here
          *(_Float16*)(otile + tbase + (size_t)(q * 4 + i) * 16) =
              (_Float16)hnew;
          pv[i] = hnew * fcw_l;
        }
        if (phase) {
#pragma unroll
          for (int i = 0; i < 4; ++i) {
            float v = pv[i];
            v += __shfl_xor(v, 1);
            v += __shfl_xor(v, 2);
            v += __shfl_xor(v, 4);
            v += __shfl_xor(v, 8);
            if (r == 0) {
              float* pb = (float*)(ws + PB) + (size_t)(d & 1) * 64 * 256;
              __hip_atomic_store(&pb[jg * 256 + (rg * 16 + q * 4 + i)], v,
                                 __ATOMIC_RELAXED, __HIP_MEMORY_SCOPE_AGENT);
            }
          }
        }
      }
      __syncthreads();

      // ---- stream h' (2KB) out: loc -> plain 8B stores (write-through,
      //      dirty in own-XCD L2, acked by the barrier's vmcnt drain
      //      BEFORE the LLC counter increment); else LLC stores ----
      if (tid < 256) {
        ull v = *(const ull*)(otile + (size_t)tid * 8);
        char* p = ws + HP + (size_t)((s + 1) & 1) * PSTR + slab +
                  (size_t)cb * 2048 + (size_t)tid * 8;
        if (loc) {
          *(volatile ull*)p = v;
        } else {
          sta8(p, v);
        }
      }

      bt += 16;
      gbar(bar, bt);
    }
  }

  // ---- final output column t = TL-1 ----
  if (cb == 0 && tid < 16) {
    const float* pb =
        (const float*)(ws + PB) + (size_t)((TL_ - 1) & 1) * 64 * 256;
    int row = rg * 16 + tid;
    float a = fcb_s;
    for (int jj = 0; jj < 64; ++jj) a += lda4f(&pb[jj * 256 + row]);
    out[(size_t)row * TL_ + (TL_ - 1)] = a;
  }
}

// ---------------------------------------------------------------------------
extern "C" void kernel_launch(void* const* d_in, const int* in_sizes, int n_in,
                              void* d_out, int out_size, void* d_ws,
                              size_t ws_size, hipStream_t stream) {
  const float* x     = (const float*)d_in[0];
  const float* WihE  = (const float*)d_in[1];
  const float* WhhE  = (const float*)d_in[2];
  const float* bihE  = (const float*)d_in[3];
  const float* bhhE  = (const float*)d_in[4];
  const float* WihD  = (const float*)d_in[5];
  const float* WhhD  = (const float*)d_in[6];
  const float* bihD  = (const float*)d_in[7];
  const float* bhhD  = (const float*)d_in[8];
  const float* fcW   = (const float*)d_in[9];
  const float* fcb   = (const float*)d_in[10];
  float* outp = (float*)d_out;
  char* ws = (char*)d_ws;

  gru_setup<<<3168, 256, 0, stream>>>(WhhE, WhhD, WihE, ws);

  gru_main<<<dim3(256), dim3(512), 0, stream>>>(
      x, bihE, bhhE, WihD, bihD, bhhD, fcW, fcb, outp, ws);
}

// Round 3
// 3658.345 us; speedup vs baseline: 1.0905x; 1.0905x over previous
//
#include <hip/hip_runtime.h>

#define B_  256
#define T_  512
#define F_  64
#define H_  1024
#define TL_ 64

typedef _Float16 half8 __attribute__((ext_vector_type(8)));
typedef float   floatx4 __attribute__((ext_vector_type(4)));
typedef unsigned long long ull;

#define MFMA(a, b, c) __builtin_amdgcn_mfma_f32_16x16x32_f16(a, b, c, 0, 0, 0)

// ws layout (bytes)
#define WF_E   0UL          // W_hh enc fragments: 3*64*32 chunks * 1024B
#define WF_D   6291456UL    // W_hh dec fragments
#define WF_I   12582912UL   // W_ih enc fragments: 3*64*2 chunks * 1024B
#define HP     12976128UL   // h planes: [2 parity][hi fp16 512KB]
#define PSTR   524288UL     // parity stride
#define PB     15073280UL   // fc partials: [2][64 jg][256 rows] f32
#define BARS   15204352UL   // 16 group counters, 128B apart (+dbar at uint 1)
// h plane (fragment-major fp16): [rg 16][kb 32][lane 64][16B]; slab 32KB/rg;
// block (rg,cb) owns the contiguous 2KB at rg*32768 + cb*2048.
// NOTE (r10): h stored fp16-only; own-recurrence stays fp32 in hold[].
// NOTE (r13 postmortem of r12): loc ENGAGED (counters moved) but `volatile`
// h'-stores lowered with cache-bypass bits -> writes crossed to LLC
// (WRITE_SIZE unchanged), LLC write probe-invalidated the XCD-L2 copies
// (why numerics stayed exact), and the aux=1 DMA then MISSED L2 and
// refilled from LLC every step (FETCH +30MB, +2.2us/step). Fix: PLAIN
// non-volatile stores -> dirty line in own XCD L2; sc0 DMA read hits it.
// Cross-dispatch staleness is covered by kernel-boundary release/acquire
// (same mechanism that makes gru_setup's plain-stored W-frags visible to
// gru_main on other XCDs — proven by every passing run).

// LLC-coherent scalar atomics (sc0 sc1: bypass L1/L2, coherent at IF).
__device__ __forceinline__ void sta8(void* p, ull v) {
  __hip_atomic_store((ull*)p, v, __ATOMIC_RELAXED, __HIP_MEMORY_SCOPE_AGENT);
}
__device__ __forceinline__ float lda4f(const float* p) {
  return __hip_atomic_load(p, __ATOMIC_RELAXED, __HIP_MEMORY_SCOPE_AGENT);
}
__device__ __forceinline__ unsigned lda4u(const unsigned* p) {
  return __hip_atomic_load(p, __ATOMIC_RELAXED, __HIP_MEMORY_SCOPE_AGENT);
}

// ---------------------------------------------------------------------------
// Setup: W_hh (enc,dec) and W_ih (enc) fp32 -> fp16 MFMA-B fragment layout.
// B-frag 16x16x32: lane L holds B[k=(L>>4)*8+t][n=L&15] ->
// W[g*H + jg*16 + (L&15)][kb*32 + (L>>4)*8 + t].
// Chunk c = (((g*64+jg)*32 + kb)*4 + q)*16 + r ; 16B per chunk-lane.
// ---------------------------------------------------------------------------
__global__ void gru_setup(const float* __restrict__ WhhE,
                          const float* __restrict__ WhhD,
                          const float* __restrict__ WihE,
                          char* __restrict__ ws) {
  int t = blockIdx.x * 256 + threadIdx.x;
  if (t < 512) ((unsigned int*)(ws + BARS))[t] = 0u;
  const int NW = 3 * 64 * 32 * 4 * 16;
  if (t < 2 * NW) {
    const float* W = (t < NW) ? WhhE : WhhD;
    size_t dst = (t < NW) ? WF_E : WF_D;
    int c = (t < NW) ? t : t - NW;
    int r = c & 15, q = (c >> 4) & 3, kb = (c >> 6) & 31, gj = c >> 11;
    int row = (gj >> 6) * H_ + (gj & 63) * 16 + r;
    const float* src = W + (size_t)row * H_ + kb * 32 + q * 8;
    half8 v;
#pragma unroll
    for (int i = 0; i < 8; ++i) v[i] = (_Float16)src[i];
    *(half8*)(ws + dst + (size_t)c * 16) = v;
  } else if (t < 2 * NW + 3 * 64 * 2 * 4 * 16) {
    int c = t - 2 * NW;
    int r = c & 15, q = (c >> 4) & 3, kc = (c >> 6) & 1, gj = c >> 7;
    int row = (gj >> 6) * H_ + (gj & 63) * 16 + r;
    const float* src = WihE + (size_t)row * F_ + kc * 32 + q * 8;
    half8 v;
#pragma unroll
    for (int i = 0; i < 8; ++i) v[i] = (_Float16)src[i];
    *(half8*)(ws + WF_I + (size_t)c * 16) = v;
  }
}

// Group barrier: 16 blocks (same rg), own cacheline, relaxed LLC atomics.
// (r10-proven mechanism; used in BOTH modes.)
__device__ __forceinline__ void gbar(unsigned int* cnt, unsigned int target) {
  __syncthreads();
  if (threadIdx.x == 0) {
    __hip_atomic_fetch_add(cnt, 1u, __ATOMIC_RELAXED,
                           __HIP_MEMORY_SCOPE_AGENT);
    while (__hip_atomic_load(cnt, __ATOMIC_RELAXED,
                             __HIP_MEMORY_SCOPE_AGENT) < target)
      __builtin_amdgcn_s_sleep(1);
  }
  __syncthreads();
}

// ---------------------------------------------------------------------------
// Main persistent kernel: 256 blocks x 512 thr. Block (rg, cb): rows
// [rg*16,+16), h-cols [cb*64,+64). Wave w: jp=w&3 (jg=cb*4+jp), kh=w>>2.
// r13: rg-groups formed from the PHYSICAL XCD (HW_REG_XCC_ID + one device
// barrier). When every XCD hosts exactly 32 blocks (2 groups of 16), the
// per-step h exchange rides the per-XCD L2: PLAIN stores (dirty in own L2,
// acked by the barrier's vmcnt drain BEFORE the LLC counter increment) +
// sc0 DMA reads (bypass L1, hit that L2). Barriers stay on the LLC path.
// Unbalanced dispatch -> loc=0 fallback, bit-identical to the r10 champion.
// ---------------------------------------------------------------------------
__global__ __launch_bounds__(512, 2) void gru_main(
    const float* __restrict__ x,
    const float* __restrict__ bih_e, const float* __restrict__ bhh_e,
    const float* __restrict__ Wih_d,
    const float* __restrict__ bih_d, const float* __restrict__ bhh_d,
    const float* __restrict__ fcW, const float* __restrict__ fcb,
    float* __restrict__ out, char* __restrict__ ws) {

  __shared__ __align__(128) char atile[32768];  // [kb 32][L 64][16B]
  __shared__ float red[4 * 64 * 17];            // kh1 partials [jp][L][17]
  __shared__ __align__(16) char otile[2048];    // h' image (2KB)
  __shared__ float inp_lds[16];
  __shared__ unsigned char xmap[256];
  __shared__ int disc[3];                       // rg, cb, loc

  const int tid = threadIdx.x;
  const int L = tid & 63;
  const int w = tid >> 6;
  const int jp = w & 3;
  const int kh = w >> 2;
  const int bx = blockIdx.x;
  const int r = L & 15;
  const int q = L >> 4;

  // ---- XCD discovery prologue (runs once; LLC-spin mechanism = r10's) ----
  {
    unsigned* map = (unsigned*)(ws + PB);
    unsigned* dbar = (unsigned*)(ws + BARS) + 1;
    if (tid == 0) {
      unsigned xcc;
      asm volatile("s_getreg_b32 %0, hwreg(HW_REG_XCC_ID)" : "=s"(xcc));
      __hip_atomic_store(map + bx, xcc & 15u, __ATOMIC_RELAXED,
                         __HIP_MEMORY_SCOPE_AGENT);
    }
    __syncthreads();  // drains vmcnt: map store is at the LLC
    if (tid == 0) {
      __hip_atomic_fetch_add(dbar, 1u, __ATOMIC_RELAXED,
                             __HIP_MEMORY_SCOPE_AGENT);
      while (lda4u(dbar) < 256u) __builtin_amdgcn_s_sleep(1);
    }
    __syncthreads();
    if (tid < 256) xmap[tid] = (unsigned char)(lda4u(map + tid) & 255u);
    __syncthreads();
    if (tid == 0) {
      int cnt[8] = {0, 0, 0, 0, 0, 0, 0, 0};
      int myx = xmap[bx], rank = 0, ok = 1;
      for (int i = 0; i < 256; ++i) {
        int xi = xmap[i];
        if (xi > 7) { ok = 0; break; }
        cnt[xi]++;
        if (i < bx && xi == myx) rank++;
      }
      if (ok)
        for (int i = 0; i < 8; ++i) ok &= (cnt[i] == 32);
      if (ok) {
        disc[0] = myx * 2 + (rank >> 4);  // 2 rgs per XCD
        disc[1] = rank & 15;
        disc[2] = 1;
      } else {
        disc[0] = bx & 15;                // r10 static mapping, LLC path
        disc[1] = bx >> 4;
        disc[2] = 0;
      }
    }
    __syncthreads();
  }
  const int rg = disc[0];
  const int cb = disc[1];
  const int loc = disc[2];  // globally uniform: every block saw the same map

  const int jg = cb * 4 + jp;
  const int jc = jg * 16 + r;

  unsigned int* bar = (unsigned int*)(ws + BARS) + (size_t)rg * 32;
  unsigned int bt = 0;

  const size_t slab = (size_t)rg * 32768;

  // zero own h'-region of parity 0 (2KB/block). Always LLC: L2 starts
  // invalidated at dispatch launch, so the first sc0 read misses L2 and
  // fills the zeros from the LLC.
  if (tid < 256) {
    sta8(ws + HP + slab + (size_t)cb * 2048 + (size_t)tid * 8, 0ull);
  }

  float hold[4] = {0.f, 0.f, 0.f, 0.f};
  const float fcb_s = *fcb;
  const float fcw_l = fcW[jc];

  bt += 16;
  gbar(bar, bt);

  for (int phase = 0; phase < 2; ++phase) {
    // register-resident W_hh B-frags for (jg, kh): [gate][kk].
    half8 bW[48];
    {
      const char* wf = ws + (phase ? WF_D : WF_E);
#pragma unroll
      for (int g = 0; g < 3; ++g)
#pragma unroll
        for (int kk = 0; kk < 16; ++kk)
          bW[g * 16 + kk] = *(const half8*)(
              wf + (size_t)((g * 64 + jg) * 32 + kh * 16 + kk) * 1024 +
              (size_t)L * 16);
#pragma unroll
      for (int i = 0; i < 48; ++i) asm volatile("" : "+v"(bW[i]));
    }
    const float* bih = phase ? bih_d : bih_e;
    const float* bhh = phase ? bhh_d : bhh_e;
    const float b_r  = bih[jc]          + bhh[jc];
    const float b_z  = bih[H_ + jc]     + bhh[H_ + jc];
    const float b_in = bih[2 * H_ + jc];
    const float b_hn = bhh[2 * H_ + jc];
    float wd_r = 0.f, wd_z = 0.f, wd_n = 0.f;
    if (phase) {
      wd_r = Wih_d[jc]; wd_z = Wih_d[H_ + jc]; wd_n = Wih_d[2 * H_ + jc];
    }

    const int nsteps = phase ? TL_ : T_;
    for (int d = 0; d < nsteps; ++d) {
      const int s = phase ? T_ + d : d;

      // ---- stage A slab (32KB) via async global->LDS DMA.
      //      loc: aux 1 (sc0, bypass L1, hit own-XCD L2 dirty lines);
      //      else aux 17 (sc0|sc1, LLC-coherent). 32 segs of 1KB; wave w
      //      takes segs w*4..w*4+3; lane L's 16B at seg base + L*16. ----
      {
        const char* srcbase = ws + HP + (size_t)(s & 1) * PSTR + slab;
        if (loc) {
#pragma unroll
          for (int c = 0; c < 4; ++c) {
            const int seg = w * 4 + c;  // 0..31
            const char* src = srcbase + (size_t)seg * 1024 + (size_t)L * 16;
            __builtin_amdgcn_global_load_lds(
                (const __attribute__((address_space(1))) void*)src,
                (__attribute__((address_space(3))) void*)(atile + seg * 1024),
                16, 0, 1);
          }
        } else {
#pragma unroll
          for (int c = 0; c < 4; ++c) {
            const int seg = w * 4 + c;
            const char* src = srcbase + (size_t)seg * 1024 + (size_t)L * 16;
            __builtin_amdgcn_global_load_lds(
                (const __attribute__((address_space(1))) void*)src,
                (__attribute__((address_space(3))) void*)(atile + seg * 1024),
                16, 0, 17);
          }
        }
      }

      // ---- decoder scalar input (overlaps the staging DMA; PB stays on
      //      the LLC path in both modes) ----
      if (phase && tid < 16) {
        float sum = 0.f;
        if (d > 0) {
          const float* pb =
              (const float*)(ws + PB) + (size_t)((d + 1) & 1) * 64 * 256;
          int row = rg * 16 + tid;
          float a = fcb_s;
          for (int jj = 0; jj < 64; ++jj) a += lda4f(&pb[jj * 256 + row]);
          sum = a;
          if (cb == 0) out[(size_t)row * TL_ + (d - 1)] = a;
        }
        inp_lds[tid] = sum;
      }
      __syncthreads();  // drains vmcnt -> DMA complete

      floatx4 a0 = {0.f, 0.f, 0.f, 0.f}, a1 = {0.f, 0.f, 0.f, 0.f};
      floatx4 a2 = {0.f, 0.f, 0.f, 0.f}, aI = {0.f, 0.f, 0.f, 0.f};

      // ---- h-GEMM, this wave's K-half (stride-1 ds_read_b128) ----
#pragma unroll
      for (int kk = 0; kk < 16; ++kk) {
        const int kb = kh * 16 + kk;
        half8 ahi = *(const half8*)(atile + kb * 1024 + L * 16);
        a0 = MFMA(ahi, bW[kk], a0);
        a1 = MFMA(ahi, bW[16 + kk], a1);
        a2 = MFMA(ahi, bW[32 + kk], a2);
      }

      // ---- kh1: encoder x-projection + dump partials ----
      if (kh == 1) {
        if (!phase) {
          const float* xp =
              x + ((size_t)(rg * 16 + r) * T_ + s) * F_ + q * 8;
          const char* wfi = ws + WF_I + (size_t)L * 16;  // L1/L2-hot reloads
#pragma unroll
          for (int kc = 0; kc < 2; ++kc) {
            floatx4 x0 = *(const floatx4*)(xp + kc * 32);
            floatx4 x1 = *(const floatx4*)(xp + kc * 32 + 4);
            half8 xa;
#pragma unroll
            for (int i = 0; i < 4; ++i) {
              xa[i] = (_Float16)x0[i];
              xa[4 + i] = (_Float16)x1[i];
            }
            a0 = MFMA(xa, *(const half8*)(wfi +
                     (size_t)((0 * 64 + jg) * 2 + kc) * 1024), a0);
            a1 = MFMA(xa, *(const half8*)(wfi +
                     (size_t)((1 * 64 + jg) * 2 + kc) * 1024), a1);
            aI = MFMA(xa, *(const half8*)(wfi +
                     (size_t)((2 * 64 + jg) * 2 + kc) * 1024), aI);
          }
        }
        float* rd = &red[(jp * 64 + L) * 17];
#pragma unroll
        for (int i = 0; i < 4; ++i) {
          rd[i] = a0[i];
          rd[4 + i] = a1[i];
          rd[8 + i] = a2[i];
        }
        if (!phase) {
#pragma unroll
          for (int i = 0; i < 4; ++i) rd[12 + i] = aI[i];
        }
      }
      __syncthreads();

      // ---- kh0: reduce halves, gate epilogue, h' -> otile ----
      if (kh == 0) {
        const float* rd = &red[(jp * 64 + L) * 17];
        const size_t tbase = (size_t)(jp >> 1) * 1024 +
                             (size_t)((jp & 1) * 2 + (r >> 3)) * 256 +
                             (size_t)(r & 7) * 2;
        float pv[4];
#pragma unroll
        for (int i = 0; i < 4; ++i) {
          float rpre = a0[i] + rd[i] + b_r;
          float zpre = a1[i] + rd[4 + i] + b_z;
          float hn   = a2[i] + rd[8 + i] + b_hn;
          float inn  = b_in + (phase ? 0.f : rd[12 + i]);
          if (phase) {
            float inp = inp_lds[q * 4 + i];
            rpre += inp * wd_r;
            zpre += inp * wd_z;
            inn  += inp * wd_n;
          }
          float rg_ = 1.f / (1.f + __expf(-rpre));
          float zg = 1.f / (1.f + __expf(-zpre));
          float t2 = __expf(-2.f * (inn + rg_ * hn));
          float ng = 2.f / (1.f + t2) - 1.f;  // tanh, safe at +-inf
          float hnew = (1.f - zg) * ng + zg * hold[i];
          hold[i] = hnew;  // fp32 carry: storage quant never compounds here
          *(_Float16*)(otile + tbase + (size_t)(q * 4 + i) * 16) =
              (_Float16)hnew;
          pv[i] = hnew * fcw_l;
        }
        if (phase) {
#pragma unroll
          for (int i = 0; i < 4; ++i) {
            float v = pv[i];
            v += __shfl_xor(v, 1);
            v += __shfl_xor(v, 2);
            v += __shfl_xor(v, 4);
            v += __shfl_xor(v, 8);
            if (r == 0) {
              float* pb = (float*)(ws + PB) + (size_t)(d & 1) * 64 * 256;
              __hip_atomic_store(&pb[jg * 256 + (rg * 16 + q * 4 + i)], v,
                                 __ATOMIC_RELAXED, __HIP_MEMORY_SCOPE_AGENT);
            }
          }
        }
      }
      __syncthreads();

      // ---- stream h' (2KB) out. loc: PLAIN stores -> dirty own-XCD L2
      //      (no sc bits; r12's volatile lowered with cache-bypass and
      //      forced LLC round trips). The gbar's __syncthreads drains
      //      vmcnt, so stores are L2-acked before the counter increment.
      //      Non-loc: LLC stores as in r10. ----
      if (tid < 256) {
        ull v = *(const ull*)(otile + (size_t)tid * 8);
        char* p = ws + HP + (size_t)((s + 1) & 1) * PSTR + slab +
                  (size_t)cb * 2048 + (size_t)tid * 8;
        if (loc) {
          *(ull*)p = v;
        } else {
          sta8(p, v);
        }
      }

      bt += 16;
      gbar(bar, bt);
    }
  }

  // ---- final output column t = TL-1 ----
  if (cb == 0 && tid < 16) {
    const float* pb =
        (const float*)(ws + PB) + (size_t)((TL_ - 1) & 1) * 64 * 256;
    int row = rg * 16 + tid;
    float a = fcb_s;
    for (int jj = 0; jj < 64; ++jj) a += lda4f(&pb[jj * 256 + row]);
    out[(size_t)row * TL_ + (TL_ - 1)] = a;
  }
}

// ---------------------------------------------------------------------------
extern "C" void kernel_launch(void* const* d_in, const int* in_sizes, int n_in,
                              void* d_out, int out_size, void* d_ws,
                              size_t ws_size, hipStream_t stream) {
  const float* x     = (const float*)d_in[0];
  const float* WihE  = (const float*)d_in[1];
  const float* WhhE  = (const float*)d_in[2];
  const float* bihE  = (const float*)d_in[3];
  const float* bhhE  = (const float*)d_in[4];
  const float* WihD  = (const float*)d_in[5];
  const float* WhhD  = (const float*)d_in[6];
  const float* bihD  = (const float*)d_in[7];
  const float* bhhD  = (const float*)d_in[8];
  const float* fcW   = (const float*)d_in[9];
  const float* fcb   = (const float*)d_in[10];
  float* outp = (float*)d_out;
  char* ws = (char*)d_ws;

  gru_setup<<<3168, 256, 0, stream>>>(WhhE, WhhD, WihE, ws);

  gru_main<<<dim3(256), dim3(512), 0, stream>>>(
      x, bihE, bhhE, WihD, bihD, bhhD, fcW, fcb, outp, ws);
}